// Round 2
// baseline (458.508 us; speedup 1.0000x reference)
//
#include <hip/hip_runtime.h>
#include <math.h>

#define EPS 1e-5f

// ---------------------------------------------------------------------------
// Generic tiled transpose: in (B, R, C) -> out (B, C, R). grid=(B, R/64, C/64)
// block = 256 threads. LDS 64x65 to avoid bank conflicts.
// ---------------------------------------------------------------------------
__global__ void transpose_k(const float* __restrict__ in, float* __restrict__ out,
                            int R, int C) {
  __shared__ float tile[64][65];
  int n = blockIdx.x;
  int r0 = blockIdx.y * 64;
  int c0 = blockIdx.z * 64;
  const float* src = in + (size_t)n * R * C;
  float* dst = out + (size_t)n * R * C;
  int lane = threadIdx.x & 63;
  int tr = threadIdx.x >> 6;  // 0..3
#pragma unroll
  for (int rr = tr; rr < 64; rr += 4)
    tile[rr][lane] = src[(size_t)(r0 + rr) * C + c0 + lane];
  __syncthreads();
#pragma unroll
  for (int cc = tr; cc < 64; cc += 4)
    dst[(size_t)(c0 + cc) * R + r0 + lane] = tile[lane][cc];
}

// ---------------------------------------------------------------------------
// K1: qkv[b,o,i] = BN( sum_c wq[o,c] * xt[b,c,i] )
// xt: (1024, 128, 128) contiguous. wq: (256,128). qkv out: (1024, 256, 128).
// grid = 2048 blocks (b*2 + o_half), block = 256 threads.
// Each thread: 8 o x 8 i register tile. K streamed in chunks of 32.
// ---------------------------------------------------------------------------
__global__ void qkv_kernel(const float* __restrict__ xt, const float* __restrict__ wq,
                           const float* __restrict__ qg, const float* __restrict__ qb,
                           const float* __restrict__ qm, const float* __restrict__ qv,
                           float* __restrict__ qkv) {
  __shared__ float xs[32][128];  // [c-chunk][i]
  __shared__ float wt[32][128];  // [c-chunk][o]  (transposed weights)
  int b = blockIdx.x >> 1;
  int oh = blockIdx.x & 1;
  int t = threadIdx.x;
  int tx = t & 15;   // i = tx*8 .. +8
  int ty = t >> 4;   // o = ty*8 .. +8 (within 128-half)
  const float* xb = xt + (size_t)b * 16384;

  float acc[8][8];
#pragma unroll
  for (int a = 0; a < 8; a++)
#pragma unroll
    for (int i2 = 0; i2 < 8; i2++) acc[a][i2] = 0.f;

  for (int c0 = 0; c0 < 128; c0 += 32) {
    // stage x chunk (coalesced float4)
    for (int idx = t; idx < 1024; idx += 256) {
      float4 vv = *(const float4*)(xb + c0 * 128 + idx * 4);
      *(float4*)(&xs[0][0] + idx * 4) = vv;
    }
    // stage weight chunk transposed
    for (int f4 = t; f4 < 1024; f4 += 256) {
      int o = f4 & 127;
      int cc4 = f4 >> 7;  // 0..7
      float4 vv = *(const float4*)(wq + (size_t)(oh * 128 + o) * 128 + c0 + cc4 * 4);
      wt[cc4 * 4 + 0][o] = vv.x;
      wt[cc4 * 4 + 1][o] = vv.y;
      wt[cc4 * 4 + 2][o] = vv.z;
      wt[cc4 * 4 + 3][o] = vv.w;
    }
    __syncthreads();
#pragma unroll 4
    for (int cc = 0; cc < 32; cc++) {
      float4 x0 = *(const float4*)&xs[cc][tx * 8];
      float4 x1 = *(const float4*)&xs[cc][tx * 8 + 4];
      float4 w0 = *(const float4*)&wt[cc][ty * 8];
      float4 w1 = *(const float4*)&wt[cc][ty * 8 + 4];
      float xv[8] = {x0.x, x0.y, x0.z, x0.w, x1.x, x1.y, x1.z, x1.w};
      float wv[8] = {w0.x, w0.y, w0.z, w0.w, w1.x, w1.y, w1.z, w1.w};
#pragma unroll
      for (int a = 0; a < 8; a++)
#pragma unroll
        for (int i2 = 0; i2 < 8; i2++)
          acc[a][i2] = fmaf(wv[a], xv[i2], acc[a][i2]);
    }
    __syncthreads();
  }

  float* dstbase = qkv + (size_t)b * 256 * 128;
#pragma unroll
  for (int a = 0; a < 8; a++) {
    int o = oh * 128 + ty * 8 + a;
    float scale = qg[o] * rsqrtf(qv[o] + EPS);
    float bias = qb[o] - qm[o] * scale;
    float o0 = fmaf(acc[a][0], scale, bias);
    float o1 = fmaf(acc[a][1], scale, bias);
    float o2 = fmaf(acc[a][2], scale, bias);
    float o3 = fmaf(acc[a][3], scale, bias);
    float o4 = fmaf(acc[a][4], scale, bias);
    float o5 = fmaf(acc[a][5], scale, bias);
    float o6 = fmaf(acc[a][6], scale, bias);
    float o7 = fmaf(acc[a][7], scale, bias);
    float* dp = dstbase + (size_t)o * 128 + tx * 8;
    *(float4*)dp = make_float4(o0, o1, o2, o3);
    *(float4*)(dp + 4) = make_float4(o4, o5, o6, o7);
  }
}

// ---------------------------------------------------------------------------
// K2: attention per (b,g). qkv (1024,256,128). Writes svout (1024,128,128)
// with output-BN applied. grid = 8192 blocks, block = 64 (one wave).
// Thread = softmax rows i0=t, i1=t+64; ONLINE softmax with running max
// (branchless rescale) — logit spread can exceed 80, a fixed shift is unsafe.
// ---------------------------------------------------------------------------
__global__ void attn_kernel(const float* __restrict__ qkv,
                            const float* __restrict__ sg, const float* __restrict__ sb,
                            const float* __restrict__ sm, const float* __restrict__ svv,
                            const float* __restrict__ og, const float* __restrict__ ob,
                            const float* __restrict__ om, const float* __restrict__ ov,
                            float* __restrict__ svout) {
  __shared__ float lds[4096];  // q:[0,1024) k:[1024,2048) v:[2048,4096), [c][i]
  int bg = blockIdx.x;
  int b = bg >> 3, g = bg & 7;
  int t = threadIdx.x;  // 0..63
  const float* src = qkv + ((size_t)b * 256 + g * 32) * 128;
#pragma unroll
  for (int k = 0; k < 16; k++) {
    int idx = (t + k * 64) * 4;
    *(float4*)&lds[idx] = *(const float4*)&src[idx];
  }
  __syncthreads();

  float s_scale = sg[g] * rsqrtf(svv[g] + EPS);
  float s_bias = sb[g] - sm[g] * s_scale;

  int i0 = t, i1 = t + 64;
  float qA[8], qB[8];
#pragma unroll
  for (int c = 0; c < 8; c++) {
    qA[c] = lds[c * 128 + i0];
    qB[c] = lds[c * 128 + i1];
  }

  float svA[16], svB[16];
#pragma unroll
  for (int c = 0; c < 16; c++) { svA[c] = 0.f; svB[c] = 0.f; }
  float lsA = 0.f, lsB = 0.f;
  float mA = -INFINITY, mB = -INFINITY;

  for (int j4 = 0; j4 < 32; j4++) {
    float kr[8][4];
#pragma unroll
    for (int c = 0; c < 8; c++) {
      float4 vv = *(const float4*)&lds[1024 + c * 128 + j4 * 4];
      kr[c][0] = vv.x; kr[c][1] = vv.y; kr[c][2] = vv.z; kr[c][3] = vv.w;
    }
    float lA[4], lB[4];
#pragma unroll
    for (int jj = 0; jj < 4; jj++) {
      float qkA = 0.f, qkB = 0.f;
#pragma unroll
      for (int c = 0; c < 8; c++) {
        qkA = fmaf(qA[c], kr[c][jj], qkA);
        qkB = fmaf(qB[c], kr[c][jj], qkB);
      }
      lA[jj] = fmaf(qkA, s_scale, s_bias);
      lB[jj] = fmaf(qkB, s_scale, s_bias);
    }
    // online max update (branchless; exp args always <= 0)
    float m4A = fmaxf(fmaxf(lA[0], lA[1]), fmaxf(lA[2], lA[3]));
    float m4B = fmaxf(fmaxf(lB[0], lB[1]), fmaxf(lB[2], lB[3]));
    float mnA = fmaxf(mA, m4A);
    float mnB = fmaxf(mB, m4B);
    float alA = __expf(mA - mnA);  // exp(-inf)=0 on first block
    float alB = __expf(mB - mnB);
    mA = mnA; mB = mnB;
    lsA *= alA; lsB *= alB;
#pragma unroll
    for (int c = 0; c < 16; c++) { svA[c] *= alA; svB[c] *= alB; }

    float eA[4], eB[4];
#pragma unroll
    for (int jj = 0; jj < 4; jj++) {
      eA[jj] = __expf(lA[jj] - mA);
      eB[jj] = __expf(lB[jj] - mB);
      lsA += eA[jj];
      lsB += eB[jj];
    }
    // v in two halves of 8 channels to cap register pressure
#pragma unroll
    for (int half = 0; half < 2; half++) {
      float vr[8][4];
#pragma unroll
      for (int c = 0; c < 8; c++) {
        float4 vv = *(const float4*)&lds[2048 + (half * 8 + c) * 128 + j4 * 4];
        vr[c][0] = vv.x; vr[c][1] = vv.y; vr[c][2] = vv.z; vr[c][3] = vv.w;
      }
#pragma unroll
      for (int jj = 0; jj < 4; jj++) {
#pragma unroll
        for (int c = 0; c < 8; c++) {
          svA[half * 8 + c] = fmaf(eA[jj], vr[c][jj], svA[half * 8 + c]);
          svB[half * 8 + c] = fmaf(eB[jj], vr[c][jj], svB[half * 8 + c]);
        }
      }
    }
  }

  float invA = 1.f / lsA, invB = 1.f / lsB;
#pragma unroll
  for (int c = 0; c < 16; c++) {
    int oc = g * 16 + c;
    float scale = og[oc] * rsqrtf(ov[oc] + EPS);
    float bias = ob[oc] - om[oc] * scale;
    float* dp = svout + ((size_t)b * 128 + oc) * 128;
    dp[i0] = fmaf(svA[c] * invA, scale, bias);
    dp[i1] = fmaf(svB[c] * invB, scale, bias);
  }
}

// ---------------------------------------------------------------------------
extern "C" void kernel_launch(void* const* d_in, const int* in_sizes, int n_in,
                              void* d_out, int out_size, void* d_ws, size_t ws_size,
                              hipStream_t stream) {
  const float* x  = (const float*)d_in[0];
  const float* wq = (const float*)d_in[1];
  const float* qg = (const float*)d_in[2];
  const float* qb = (const float*)d_in[3];
  const float* qm = (const float*)d_in[4];
  const float* qv = (const float*)d_in[5];
  const float* sg = (const float*)d_in[6];
  const float* sb = (const float*)d_in[7];
  const float* sm = (const float*)d_in[8];
  const float* sv = (const float*)d_in[9];
  const float* og = (const float*)d_in[10];
  const float* ob = (const float*)d_in[11];
  const float* om = (const float*)d_in[12];
  const float* ov = (const float*)d_in[13];
  float* out = (float*)d_out;

  // workspace: qkvbuf 1024*256*128 fp32 (128 MB) + xbuf/svbuf 1024*128*128 fp32 (64 MB)
  float* qkvbuf = (float*)d_ws;
  float* xbuf = qkvbuf + (size_t)1024 * 256 * 128;

  // K0: x (8, 16384(c*h), 128(w)) -> xt (8, 128(w), 16384(c*h)) == (b, c, i)
  transpose_k<<<dim3(8, 256, 2), 256, 0, stream>>>(x, xbuf, 16384, 128);
  // K1: qkv GEMM + BN
  qkv_kernel<<<2048, 256, 0, stream>>>(xbuf, wq, qg, qb, qm, qv, qkvbuf);
  // K2: attention + out-BN -> svbuf (reuses xbuf region)
  attn_kernel<<<8192, 64, 0, stream>>>(qkvbuf, sg, sb, sm, sv, og, ob, om, ov, xbuf);
  // K3: svbuf (8, 128(w), 16384(o*i)) -> out (8, 16384(o*i), 128(w)) = (N,O,H,W)
  transpose_k<<<dim3(8, 2, 256), 256, 0, stream>>>(xbuf, out, 128, 16384);
}

// Round 3
// 377.202 us; speedup vs baseline: 1.2156x; 1.2156x over previous
//
#include <hip/hip_runtime.h>
#include <math.h>

#define EPS 1e-5f

typedef _Float16 half8 __attribute__((ext_vector_type(8)));
typedef float floatx4 __attribute__((ext_vector_type(4)));

// ---------------------------------------------------------------------------
// K0: x (N,C,H,W) fp32 -> xt2[b=(n,w)][i=h][c] fp16.
// Per (n,h): transpose 128x128 (c,w) -> (w,c). grid=(1024, 2, 2), block=256.
// ---------------------------------------------------------------------------
__global__ void transpose_cvt_k(const float* __restrict__ x, _Float16* __restrict__ xt2) {
  __shared__ float tile[64][65];
  int nh = blockIdx.x;
  int n = nh >> 7, h = nh & 127;
  int c0 = blockIdx.y * 64, w0 = blockIdx.z * 64;
  const float* src = x + (size_t)n * 2097152 + (size_t)h * 128;  // (c,w): src[c*16384 + w]
  _Float16* dst = xt2 + (size_t)n * 2097152 + (size_t)h * 128;   // (w,c): dst[w*16384 + c]
  int lane = threadIdx.x & 63;
  int tr = threadIdx.x >> 6;
#pragma unroll
  for (int rr = tr; rr < 64; rr += 4)
    tile[rr][lane] = src[(size_t)(c0 + rr) * 16384 + w0 + lane];
  __syncthreads();
#pragma unroll
  for (int cc = tr; cc < 64; cc += 4)
    dst[(size_t)(w0 + cc) * 16384 + c0 + lane] = (_Float16)tile[lane][cc];
}

// ---------------------------------------------------------------------------
// K1: qkv16[b][o][i] = fp16( BN( sum_c W[o][c] * xt2[b][i][c] ) )
// f16 MFMA 16x16x32. Block = (b, o-half): C-tile 128(o) x 128(i), K=128.
// 4 waves, each 64x64 quadrant = 4x4 tiles of 16x16. grid=2048, block=256.
// LDS: As[o][c], Bs[i][c] fp16 stride 136 (2-way bank aliasing = free).
// ---------------------------------------------------------------------------
__global__ void __launch_bounds__(256, 2) qkv_mfma_kernel(
    const _Float16* __restrict__ xt2, const float* __restrict__ wq,
    const float* __restrict__ qg, const float* __restrict__ qb,
    const float* __restrict__ qm, const float* __restrict__ qv,
    _Float16* __restrict__ qkv16) {
  __shared__ _Float16 As[128][136];
  __shared__ _Float16 Bs[128][136];
  __shared__ float scs[128];
  __shared__ float bis[128];
  int b = blockIdx.x >> 1;
  int oh = blockIdx.x & 1;
  int t = threadIdx.x;

  // stage A: weights fp32 -> fp16
  {
    const float* wbase = wq + (size_t)oh * 128 * 128;
#pragma unroll
    for (int idx = t; idx < 4096; idx += 256) {  // 128 rows x 32 float4
      int o = idx >> 5, c4 = (idx & 31) * 4;
      float4 v = *(const float4*)(wbase + (size_t)o * 128 + c4);
      As[o][c4 + 0] = (_Float16)v.x;
      As[o][c4 + 1] = (_Float16)v.y;
      As[o][c4 + 2] = (_Float16)v.z;
      As[o][c4 + 3] = (_Float16)v.w;
    }
  }
  // stage B: xt2 rows (already fp16, contiguous)
  {
    const _Float16* xb = xt2 + (size_t)b * 16384;
#pragma unroll
    for (int idx = t; idx < 2048; idx += 256) {  // 128 rows x 16 half8
      int i = idx >> 4, c8 = (idx & 15) * 8;
      half8 v = *(const half8*)(xb + (size_t)i * 128 + c8);
      *(half8*)(&Bs[i][c8]) = v;
    }
  }
  // BN coefficients for this o-half
  if (t < 128) {
    int o = oh * 128 + t;
    float sc = qg[o] * rsqrtf(qv[o] + EPS);
    scs[t] = sc;
    bis[t] = qb[o] - qm[o] * sc;
  }
  __syncthreads();

  int wv = t >> 6;
  int lane = t & 63;
  int m0 = (wv & 1) * 64;
  int n0 = (wv >> 1) * 64;
  int lrow = lane & 15;
  int quad = lane >> 4;

  floatx4 acc[4][4];
#pragma unroll
  for (int mt = 0; mt < 4; mt++)
#pragma unroll
    for (int nt = 0; nt < 4; nt++)
#pragma unroll
      for (int r = 0; r < 4; r++) acc[mt][nt][r] = 0.f;

#pragma unroll
  for (int k0 = 0; k0 < 128; k0 += 32) {
    half8 af[4], bf[4];
#pragma unroll
    for (int mt = 0; mt < 4; mt++)
      af[mt] = *(const half8*)(&As[m0 + mt * 16 + lrow][k0 + quad * 8]);
#pragma unroll
    for (int nt = 0; nt < 4; nt++)
      bf[nt] = *(const half8*)(&Bs[n0 + nt * 16 + lrow][k0 + quad * 8]);
#pragma unroll
    for (int mt = 0; mt < 4; mt++)
#pragma unroll
      for (int nt = 0; nt < 4; nt++)
        acc[mt][nt] = __builtin_amdgcn_mfma_f32_16x16x32_f16(af[mt], bf[nt], acc[mt][nt], 0, 0, 0);
  }

  // epilogue: BN + fp16 store. C/D: col(n)=lane&15, row(m)=quad*4+reg.
  _Float16* outb = qkv16 + (size_t)b * 32768 + (size_t)oh * 16384;
#pragma unroll
  for (int mt = 0; mt < 4; mt++) {
#pragma unroll
    for (int r = 0; r < 4; r++) {
      int o_l = m0 + mt * 16 + quad * 4 + r;
      float sc = scs[o_l];
      float bi = bis[o_l];
#pragma unroll
      for (int nt = 0; nt < 4; nt++) {
        int i = n0 + nt * 16 + lrow;
        outb[(size_t)o_l * 128 + i] = (_Float16)fmaf(acc[mt][nt][r], sc, bi);
      }
    }
  }
}

// ---------------------------------------------------------------------------
// K2: attention per (b,g). qkv16 (1024,256,128) fp16. Writes svout fp32
// (1024,128,128) with out-BN. grid=8192, block=64 (one wave).
// LDS: only k (8ch) + v (16ch) as fp32 = 12 KB -> ~13 blocks/CU.
// q loaded per-thread from global, pre-scaled by s_scale.
// Online softmax with running max (branchless rescale).
// ---------------------------------------------------------------------------
__global__ void attn_kernel(const _Float16* __restrict__ qkv16,
                            const float* __restrict__ sg, const float* __restrict__ sb,
                            const float* __restrict__ sm, const float* __restrict__ svv,
                            const float* __restrict__ og, const float* __restrict__ ob,
                            const float* __restrict__ om, const float* __restrict__ ov,
                            float* __restrict__ svout) {
  __shared__ float k_lds[1024];   // [c][i], c=0..7
  __shared__ float v_lds[2048];   // [c][i], c=0..15
  int bg = blockIdx.x;
  int b = bg >> 3, g = bg & 7;
  int t = threadIdx.x;  // 0..63

  const _Float16* base = qkv16 + (size_t)b * 32768 + (size_t)g * 32 * 128;
  // stage k (channels 8..15 of group): 1024 halves
#pragma unroll
  for (int ch = 0; ch < 2; ch++) {
    int idx = (ch * 64 + t) * 8;
    half8 hv = *(const half8*)(base + 1024 + idx);
    float4 f0 = make_float4((float)hv[0], (float)hv[1], (float)hv[2], (float)hv[3]);
    float4 f1 = make_float4((float)hv[4], (float)hv[5], (float)hv[6], (float)hv[7]);
    *(float4*)&k_lds[idx] = f0;
    *(float4*)&k_lds[idx + 4] = f1;
  }
  // stage v (channels 16..31): 2048 halves
#pragma unroll
  for (int ch = 0; ch < 4; ch++) {
    int idx = (ch * 64 + t) * 8;
    half8 hv = *(const half8*)(base + 2048 + idx);
    float4 f0 = make_float4((float)hv[0], (float)hv[1], (float)hv[2], (float)hv[3]);
    float4 f1 = make_float4((float)hv[4], (float)hv[5], (float)hv[6], (float)hv[7]);
    *(float4*)&v_lds[idx] = f0;
    *(float4*)&v_lds[idx + 4] = f1;
  }

  float s_scale = sg[g] * rsqrtf(svv[g] + EPS);
  float s_bias = sb[g] - sm[g] * s_scale;

  int i0 = t, i1 = t + 64;
  // q per-thread from global (channels 0..7), pre-scaled by s_scale
  float qA[8], qB[8];
#pragma unroll
  for (int c = 0; c < 8; c++) {
    qA[c] = (float)base[c * 128 + i0] * s_scale;
    qB[c] = (float)base[c * 128 + i1] * s_scale;
  }
  __syncthreads();

  float svA[16], svB[16];
#pragma unroll
  for (int c = 0; c < 16; c++) { svA[c] = 0.f; svB[c] = 0.f; }
  float lsA = 0.f, lsB = 0.f;
  float mA = -INFINITY, mB = -INFINITY;

  for (int j4 = 0; j4 < 32; j4++) {
    float kr[8][4];
#pragma unroll
    for (int c = 0; c < 8; c++) {
      float4 vv = *(const float4*)&k_lds[c * 128 + j4 * 4];
      kr[c][0] = vv.x; kr[c][1] = vv.y; kr[c][2] = vv.z; kr[c][3] = vv.w;
    }
    float lA[4], lB[4];
#pragma unroll
    for (int jj = 0; jj < 4; jj++) {
      float qkA = 0.f, qkB = 0.f;
#pragma unroll
      for (int c = 0; c < 8; c++) {
        qkA = fmaf(qA[c], kr[c][jj], qkA);
        qkB = fmaf(qB[c], kr[c][jj], qkB);
      }
      lA[jj] = qkA + s_bias;
      lB[jj] = qkB + s_bias;
    }
    // online max update (branchless; exp args always <= 0)
    float m4A = fmaxf(fmaxf(lA[0], lA[1]), fmaxf(lA[2], lA[3]));
    float m4B = fmaxf(fmaxf(lB[0], lB[1]), fmaxf(lB[2], lB[3]));
    float mnA = fmaxf(mA, m4A);
    float mnB = fmaxf(mB, m4B);
    float alA = __expf(mA - mnA);  // exp(-inf)=0 on first block
    float alB = __expf(mB - mnB);
    mA = mnA; mB = mnB;
    lsA *= alA; lsB *= alB;
#pragma unroll
    for (int c = 0; c < 16; c++) { svA[c] *= alA; svB[c] *= alB; }

    float eA[4], eB[4];
#pragma unroll
    for (int jj = 0; jj < 4; jj++) {
      eA[jj] = __expf(lA[jj] - mA);
      eB[jj] = __expf(lB[jj] - mB);
      lsA += eA[jj];
      lsB += eB[jj];
    }
#pragma unroll
    for (int half = 0; half < 2; half++) {
      float vr[8][4];
#pragma unroll
      for (int c = 0; c < 8; c++) {
        float4 vv = *(const float4*)&v_lds[(half * 8 + c) * 128 + j4 * 4];
        vr[c][0] = vv.x; vr[c][1] = vv.y; vr[c][2] = vv.z; vr[c][3] = vv.w;
      }
#pragma unroll
      for (int jj = 0; jj < 4; jj++) {
#pragma unroll
        for (int c = 0; c < 8; c++) {
          svA[half * 8 + c] = fmaf(eA[jj], vr[c][jj], svA[half * 8 + c]);
          svB[half * 8 + c] = fmaf(eB[jj], vr[c][jj], svB[half * 8 + c]);
        }
      }
    }
  }

  float invA = 1.f / lsA, invB = 1.f / lsB;
#pragma unroll
  for (int c = 0; c < 16; c++) {
    int oc = g * 16 + c;
    float scale = og[oc] * rsqrtf(ov[oc] + EPS);
    float bias = ob[oc] - om[oc] * scale;
    float* dp = svout + ((size_t)b * 128 + oc) * 128;
    dp[i0] = fmaf(svA[c] * invA, scale, bias);
    dp[i1] = fmaf(svB[c] * invB, scale, bias);
  }
}

// ---------------------------------------------------------------------------
// K3: generic tiled fp32 transpose: in (B, R, C) -> out (B, C, R).
// ---------------------------------------------------------------------------
__global__ void transpose_k(const float* __restrict__ in, float* __restrict__ out,
                            int R, int C) {
  __shared__ float tile[64][65];
  int n = blockIdx.x;
  int r0 = blockIdx.y * 64;
  int c0 = blockIdx.z * 64;
  const float* src = in + (size_t)n * R * C;
  float* dst = out + (size_t)n * R * C;
  int lane = threadIdx.x & 63;
  int tr = threadIdx.x >> 6;
#pragma unroll
  for (int rr = tr; rr < 64; rr += 4)
    tile[rr][lane] = src[(size_t)(r0 + rr) * C + c0 + lane];
  __syncthreads();
#pragma unroll
  for (int cc = tr; cc < 64; cc += 4)
    dst[(size_t)(c0 + cc) * R + r0 + lane] = tile[lane][cc];
}

// ---------------------------------------------------------------------------
extern "C" void kernel_launch(void* const* d_in, const int* in_sizes, int n_in,
                              void* d_out, int out_size, void* d_ws, size_t ws_size,
                              hipStream_t stream) {
  const float* x  = (const float*)d_in[0];
  const float* wq = (const float*)d_in[1];
  const float* qg = (const float*)d_in[2];
  const float* qb = (const float*)d_in[3];
  const float* qm = (const float*)d_in[4];
  const float* qv = (const float*)d_in[5];
  const float* sg = (const float*)d_in[6];
  const float* sb = (const float*)d_in[7];
  const float* sm = (const float*)d_in[8];
  const float* sv = (const float*)d_in[9];
  const float* og = (const float*)d_in[10];
  const float* ob = (const float*)d_in[11];
  const float* om = (const float*)d_in[12];
  const float* ov = (const float*)d_in[13];
  float* out = (float*)d_out;

  // workspace: qkv16 64MB | xt2 32MB | svbuf 64MB  (160 MB total)
  _Float16* qkv16 = (_Float16*)d_ws;
  _Float16* xt2 = qkv16 + (size_t)1024 * 256 * 128;           // +32M halves = 64MB
  float* svbuf = (float*)(xt2 + (size_t)1024 * 128 * 128);    // +16M halves = 32MB

  // K0: x -> xt2[b][i][c] fp16
  transpose_cvt_k<<<dim3(1024, 2, 2), 256, 0, stream>>>(x, xt2);
  // K1: f16 MFMA GEMM + BN -> qkv16[b][o][i] fp16
  qkv_mfma_kernel<<<2048, 256, 0, stream>>>(xt2, wq, qg, qb, qm, qv, qkv16);
  // K2: attention + out-BN -> svbuf fp32
  attn_kernel<<<8192, 64, 0, stream>>>(qkv16, sg, sb, sm, sv, og, ob, om, ov, svbuf);
  // K3: svbuf (8, 128w, 16384) -> out (8, 16384, 128w) = (N,O,H,W)
  transpose_k<<<dim3(8, 2, 256), 256, 0, stream>>>(svbuf, out, 128, 16384);
}

// Round 4
// 262.168 us; speedup vs baseline: 1.7489x; 1.4388x over previous
//
#include <hip/hip_runtime.h>
#include <math.h>

#define EPS 1e-5f

typedef _Float16 half4 __attribute__((ext_vector_type(4)));
typedef _Float16 half8 __attribute__((ext_vector_type(8)));
typedef float floatx4 __attribute__((ext_vector_type(4)));

// ---------------------------------------------------------------------------
// K0: x (N,C,H,W) fp32 -> xt2[b=(n,w)][i=h][c] fp16.
// Per (n,h): transpose 128x128 (c,w) -> (w,c). grid=(1024, 2, 2), block=256.
// ---------------------------------------------------------------------------
__global__ void transpose_cvt_k(const float* __restrict__ x, _Float16* __restrict__ xt2) {
  __shared__ float tile[64][65];
  int nh = blockIdx.x;
  int n = nh >> 7, h = nh & 127;
  int c0 = blockIdx.y * 64, w0 = blockIdx.z * 64;
  const float* src = x + (size_t)n * 2097152 + (size_t)h * 128;  // (c,w): src[c*16384 + w]
  _Float16* dst = xt2 + (size_t)n * 2097152 + (size_t)h * 128;   // (w,c): dst[w*16384 + c]
  int lane = threadIdx.x & 63;
  int tr = threadIdx.x >> 6;
#pragma unroll
  for (int rr = tr; rr < 64; rr += 4)
    tile[rr][lane] = src[(size_t)(c0 + rr) * 16384 + w0 + lane];
  __syncthreads();
#pragma unroll
  for (int cc = tr; cc < 64; cc += 4)
    dst[(size_t)(w0 + cc) * 16384 + c0 + lane] = (_Float16)tile[lane][cc];
}

// ---------------------------------------------------------------------------
// K1: qkv16[b][o][i] = fp16( BN( sum_c W[o][c] * xt2[b][i][c] ) )
// f16 MFMA 16x16x32. Block = (b, o-half): C-tile 128(o) x 128(i), K=128.
// ---------------------------------------------------------------------------
__global__ void __launch_bounds__(256, 2) qkv_mfma_kernel(
    const _Float16* __restrict__ xt2, const float* __restrict__ wq,
    const float* __restrict__ qg, const float* __restrict__ qb,
    const float* __restrict__ qm, const float* __restrict__ qv,
    _Float16* __restrict__ qkv16) {
  __shared__ _Float16 As[128][136];
  __shared__ _Float16 Bs[128][136];
  __shared__ float scs[128];
  __shared__ float bis[128];
  int b = blockIdx.x >> 1;
  int oh = blockIdx.x & 1;
  int t = threadIdx.x;

  {
    const float* wbase = wq + (size_t)oh * 128 * 128;
#pragma unroll
    for (int idx = t; idx < 4096; idx += 256) {
      int o = idx >> 5, c4 = (idx & 31) * 4;
      float4 v = *(const float4*)(wbase + (size_t)o * 128 + c4);
      As[o][c4 + 0] = (_Float16)v.x;
      As[o][c4 + 1] = (_Float16)v.y;
      As[o][c4 + 2] = (_Float16)v.z;
      As[o][c4 + 3] = (_Float16)v.w;
    }
  }
  {
    const _Float16* xb = xt2 + (size_t)b * 16384;
#pragma unroll
    for (int idx = t; idx < 2048; idx += 256) {
      int i = idx >> 4, c8 = (idx & 15) * 8;
      half8 v = *(const half8*)(xb + (size_t)i * 128 + c8);
      *(half8*)(&Bs[i][c8]) = v;
    }
  }
  if (t < 128) {
    int o = oh * 128 + t;
    float sc = qg[o] * rsqrtf(qv[o] + EPS);
    scs[t] = sc;
    bis[t] = qb[o] - qm[o] * sc;
  }
  __syncthreads();

  int wv = t >> 6;
  int lane = t & 63;
  int m0 = (wv & 1) * 64;
  int n0 = (wv >> 1) * 64;
  int lrow = lane & 15;
  int quad = lane >> 4;

  floatx4 acc[4][4];
#pragma unroll
  for (int mt = 0; mt < 4; mt++)
#pragma unroll
    for (int nt = 0; nt < 4; nt++)
#pragma unroll
      for (int r = 0; r < 4; r++) acc[mt][nt][r] = 0.f;

#pragma unroll
  for (int k0 = 0; k0 < 128; k0 += 32) {
    half8 af[4], bf[4];
#pragma unroll
    for (int mt = 0; mt < 4; mt++)
      af[mt] = *(const half8*)(&As[m0 + mt * 16 + lrow][k0 + quad * 8]);
#pragma unroll
    for (int nt = 0; nt < 4; nt++)
      bf[nt] = *(const half8*)(&Bs[n0 + nt * 16 + lrow][k0 + quad * 8]);
#pragma unroll
    for (int mt = 0; mt < 4; mt++)
#pragma unroll
      for (int nt = 0; nt < 4; nt++)
        acc[mt][nt] = __builtin_amdgcn_mfma_f32_16x16x32_f16(af[mt], bf[nt], acc[mt][nt], 0, 0, 0);
  }

  _Float16* outb = qkv16 + (size_t)b * 32768 + (size_t)oh * 16384;
#pragma unroll
  for (int mt = 0; mt < 4; mt++) {
#pragma unroll
    for (int r = 0; r < 4; r++) {
      int o_l = m0 + mt * 16 + quad * 4 + r;
      float sc = scs[o_l];
      float bi = bis[o_l];
#pragma unroll
      for (int nt = 0; nt < 4; nt++) {
        int i = n0 + nt * 16 + lrow;
        outb[(size_t)o_l * 128 + i] = (_Float16)fmaf(acc[mt][nt][r], sc, bi);
      }
    }
  }
}

// ---------------------------------------------------------------------------
// K2: MFMA attention, one wave per (b,g). grid=8192, block=64.
// qkv16[b][g*32 + ch][i]: q=ch 0..7, k=8..15, v=16..31 (fp16).
// S^T[j][i] = sum_ch k[ch][j] q[ch][i] via mfma(A=k^T, B=q^T). K=8 channels
// replicated across all 4 quads => S_mfma = 4*S, folded into sc4=s_scale/4
// (permutation-invariance of the k-dim makes this robust to the exact
//  (quad,jj)->k mapping, as long as A and B share it).
// C-layout: col(lane&15)=i, row(quad*4+r)=j -> softmax over j = per-lane
// partial + shfl_xor(16,32); lane holds 4 CONSECUTIVE j => P->LDS as
// ds_write_b64 fp16, read back as b128 B-frags for PV (K=128, v in regs).
// O C-layout: col=i (coalesced stores), row=c. Out-BN fused; svout fp16.
// ---------------------------------------------------------------------------
__global__ void __launch_bounds__(64) attn_mfma_kernel(
    const _Float16* __restrict__ qkv16,
    const float* __restrict__ sg, const float* __restrict__ sb,
    const float* __restrict__ sm, const float* __restrict__ svv,
    const float* __restrict__ og, const float* __restrict__ ob,
    const float* __restrict__ om, const float* __restrict__ ov,
    _Float16* __restrict__ svout) {
  __shared__ _Float16 plds[16 * 136];  // P[i][j] fp16, row stride 136 halves
  int bg = blockIdx.x;
  int b = bg >> 3, g = bg & 7;
  int t = threadIdx.x;  // 0..63
  int n = t & 15;       // lane&15: i (or j_local for kf)
  int q4 = t >> 4;      // quad

  const _Float16* base = qkv16 + (size_t)b * 32768 + (size_t)g * 4096;
  const _Float16* kb = base + 1024;
  const _Float16* vb = base + 2048;

  // k fragments (A-operand), all j-tiles, channels replicated per quad
  half8 kf[8];
#pragma unroll
  for (int jt = 0; jt < 8; jt++)
#pragma unroll
    for (int jj = 0; jj < 8; jj++)
      kf[jt][jj] = kb[jj * 128 + jt * 16 + n];

  // v fragments (A-operand for PV): lane&15 = c, 8 consecutive j per quad
  half8 vf[4];
#pragma unroll
  for (int ks = 0; ks < 4; ks++)
    vf[ks] = *(const half8*)(vb + (size_t)n * 128 + ks * 32 + q4 * 8);

  float s_scale = sg[g] * rsqrtf(svv[g] + EPS);
  float sc4 = s_scale * 0.25f;  // /4 for the quad replication
  float s_bias = sb[g] - sm[g] * s_scale;

  // out-BN coeffs for this lane's O rows c = q4*4 + r
  float osc[4], obi[4];
#pragma unroll
  for (int r = 0; r < 4; r++) {
    int oc = g * 16 + q4 * 4 + r;
    float s0 = og[oc] * rsqrtf(ov[oc] + EPS);
    osc[r] = s0;
    obi[r] = ob[oc] - om[oc] * s0;
  }

  for (int st8 = 0; st8 < 8; st8++) {
    // q fragment (B-operand) for i-strip st8
    half8 qf;
#pragma unroll
    for (int jj = 0; jj < 8; jj++)
      qf[jj] = base[jj * 128 + st8 * 16 + n];

    // S^T tiles: C[j][i], 8 j-tiles
    floatx4 stt[8];
#pragma unroll
    for (int jt = 0; jt < 8; jt++) {
      floatx4 z = {0.f, 0.f, 0.f, 0.f};
      stt[jt] = __builtin_amdgcn_mfma_f32_16x16x32_f16(kf[jt], qf, z, 0, 0, 0);
    }

    // BN logits + column softmax (over j = regs/quads)
    float mx = -1e30f;
#pragma unroll
    for (int jt = 0; jt < 8; jt++)
#pragma unroll
      for (int r = 0; r < 4; r++) {
        stt[jt][r] = fmaf(stt[jt][r], sc4, s_bias);
        mx = fmaxf(mx, stt[jt][r]);
      }
    mx = fmaxf(mx, __shfl_xor(mx, 16));
    mx = fmaxf(mx, __shfl_xor(mx, 32));

    float ls = 0.f;
#pragma unroll
    for (int jt = 0; jt < 8; jt++)
#pragma unroll
      for (int r = 0; r < 4; r++) {
        float e = __expf(stt[jt][r] - mx);
        stt[jt][r] = e;
        ls += e;
      }
    ls += __shfl_xor(ls, 16);
    ls += __shfl_xor(ls, 32);

    // P -> LDS fp16: lane holds P[i=n][j = jt*16 + q4*4 + r], 4 consecutive j
#pragma unroll
    for (int jt = 0; jt < 8; jt++) {
      half4 h;
      h[0] = (_Float16)stt[jt][0];
      h[1] = (_Float16)stt[jt][1];
      h[2] = (_Float16)stt[jt][2];
      h[3] = (_Float16)stt[jt][3];
      *(half4*)(&plds[n * 136 + jt * 16 + q4 * 4]) = h;
    }

    // PV: O[c][i] = sum_j v[c][j] P[i][j], K=128 in 4 steps
    floatx4 oacc = {0.f, 0.f, 0.f, 0.f};
#pragma unroll
    for (int ks = 0; ks < 4; ks++) {
      half8 pf = *(const half8*)(&plds[n * 136 + ks * 32 + q4 * 8]);
      oacc = __builtin_amdgcn_mfma_f32_16x16x32_f16(vf[ks], pf, oacc, 0, 0, 0);
    }

    // epilogue: normalize + out-BN; stores coalesced (16 lanes = 64B... fp16: 32B)
    float invl = 1.f / ls;
    _Float16* outp = svout + ((size_t)b * 128 + g * 16 + q4 * 4) * 128 + st8 * 16 + n;
#pragma unroll
    for (int r = 0; r < 4; r++)
      outp[(size_t)r * 128] = (_Float16)fmaf(oacc[r] * invl, osc[r], obi[r]);
  }
}

// ---------------------------------------------------------------------------
// K3: tiled transpose fp16 -> fp32: in (B, R, C) -> out (B, C, R).
// ---------------------------------------------------------------------------
__global__ void transpose_h2f_k(const _Float16* __restrict__ in, float* __restrict__ out,
                                int R, int C) {
  __shared__ float tile[64][65];
  int nblk = blockIdx.x;
  int r0 = blockIdx.y * 64;
  int c0 = blockIdx.z * 64;
  const _Float16* src = in + (size_t)nblk * R * C;
  float* dst = out + (size_t)nblk * R * C;
  int lane = threadIdx.x & 63;
  int tr = threadIdx.x >> 6;
#pragma unroll
  for (int rr = tr; rr < 64; rr += 4)
    tile[rr][lane] = (float)src[(size_t)(r0 + rr) * C + c0 + lane];
  __syncthreads();
#pragma unroll
  for (int cc = tr; cc < 64; cc += 4)
    dst[(size_t)(c0 + cc) * R + r0 + lane] = tile[lane][cc];
}

// ---------------------------------------------------------------------------
extern "C" void kernel_launch(void* const* d_in, const int* in_sizes, int n_in,
                              void* d_out, int out_size, void* d_ws, size_t ws_size,
                              hipStream_t stream) {
  const float* x  = (const float*)d_in[0];
  const float* wq = (const float*)d_in[1];
  const float* qg = (const float*)d_in[2];
  const float* qb = (const float*)d_in[3];
  const float* qm = (const float*)d_in[4];
  const float* qv = (const float*)d_in[5];
  const float* sg = (const float*)d_in[6];
  const float* sb = (const float*)d_in[7];
  const float* sm = (const float*)d_in[8];
  const float* sv = (const float*)d_in[9];
  const float* og = (const float*)d_in[10];
  const float* ob = (const float*)d_in[11];
  const float* om = (const float*)d_in[12];
  const float* ov = (const float*)d_in[13];
  float* out = (float*)d_out;

  // workspace: qkv16 64MB | xt2 32MB | svh 32MB  (128 MB total)
  _Float16* qkv16 = (_Float16*)d_ws;
  _Float16* xt2 = qkv16 + (size_t)1024 * 256 * 128;
  _Float16* svh = xt2 + (size_t)1024 * 128 * 128;

  // K0: x -> xt2[b][i][c] fp16
  transpose_cvt_k<<<dim3(1024, 2, 2), 256, 0, stream>>>(x, xt2);
  // K1: f16 MFMA GEMM + BN -> qkv16[b][o][i] fp16
  qkv_mfma_kernel<<<2048, 256, 0, stream>>>(xt2, wq, qg, qb, qm, qv, qkv16);
  // K2: MFMA attention + out-BN -> svh fp16
  attn_mfma_kernel<<<8192, 64, 0, stream>>>(qkv16, sg, sb, sm, sv, og, ob, om, ov, svh);
  // K3: svh (8, 128w, 16384oi) fp16 -> out (8, 16384, 128w) fp32 = (N,O,H,W)
  transpose_h2f_k<<<dim3(8, 2, 256), 256, 0, stream>>>(svh, out, 128, 16384);
}